// Round 15
// baseline (1878.288 us; speedup 1.0000x reference)
//
#include <hip/hip_runtime.h>

#define TOKENS 4096
#define HD 2048
#define FF 8192
#define NE 8
#define NS 2

typedef __attribute__((ext_vector_type(8))) short bf16x8;
typedef __attribute__((ext_vector_type(4))) float f32x4;

__device__ __forceinline__ unsigned rnd_bf(unsigned u) {
  return u + 0x7fffu + ((u >> 16) & 1u);
}
__device__ __forceinline__ unsigned short f2bf(float f) {
  unsigned u = __builtin_bit_cast(unsigned, f);
  return (unsigned short)(rnd_bf(u) >> 16);
}

#define GLDS16(gp, lp)                                                         \
  __builtin_amdgcn_global_load_lds(                                            \
      (const __attribute__((address_space(1))) unsigned*)(const void*)(gp),    \
      (__attribute__((address_space(3))) unsigned*)(lp), 16, 0, 0)

// ---------------- router (fused: also emits xb bf16) ----------------
__global__ void router_kernel(const float* __restrict__ x, const float* __restrict__ wg,
                              float* __restrict__ logits_out, int* __restrict__ topi,
                              float* __restrict__ topv, int* __restrict__ counts,
                              unsigned short* __restrict__ xb) {
  const int wave = threadIdx.x >> 6, lane = threadIdx.x & 63;
  const int t = blockIdx.x * 4 + wave;
  const float* xr = x + (size_t)t * HD;
  unsigned short* xbr = xb + (size_t)t * HD;
  float acc[8];
#pragma unroll
  for (int e = 0; e < 8; ++e) acc[e] = 0.f;
  for (int d = lane; d < HD; d += 64) {
    const float xv = xr[d];
    xbr[d] = f2bf(xv);
    const float4 w0 = *(const float4*)(wg + (size_t)d * 8);
    const float4 w1 = *(const float4*)(wg + (size_t)d * 8 + 4);
    acc[0] += xv * w0.x; acc[1] += xv * w0.y; acc[2] += xv * w0.z; acc[3] += xv * w0.w;
    acc[4] += xv * w1.x; acc[5] += xv * w1.y; acc[6] += xv * w1.z; acc[7] += xv * w1.w;
  }
#pragma unroll
  for (int e = 0; e < 8; ++e) {
#pragma unroll
    for (int off = 32; off > 0; off >>= 1) acc[e] += __shfl_xor(acc[e], off);
  }
  if (lane == 0) {
    *(float4*)(logits_out + (size_t)t * 8)     = make_float4(acc[0], acc[1], acc[2], acc[3]);
    *(float4*)(logits_out + (size_t)t * 8 + 4) = make_float4(acc[4], acc[5], acc[6], acc[7]);
    float mx = acc[0];
#pragma unroll
    for (int e = 1; e < 8; ++e) mx = fmaxf(mx, acc[e]);
    float p[8], s = 0.f;
#pragma unroll
    for (int e = 0; e < 8; ++e) { p[e] = expf(acc[e] - mx); s += p[e]; }
    const float inv = 1.f / s;
    int i1 = 0;
#pragma unroll
    for (int e = 1; e < 8; ++e) if (acc[e] > acc[i1]) i1 = e;
    int i2 = (i1 == 0) ? 1 : 0;
#pragma unroll
    for (int e = 0; e < 8; ++e) if (e != i1 && acc[e] > acc[i2]) i2 = e;
    topi[2 * t]     = i1; topv[2 * t]     = p[i1] * inv;
    topi[2 * t + 1] = i2; topv[2 * t + 1] = p[i2] * inv;
    atomicAdd(&counts[i1], 1);
    atomicAdd(&counts[i2], 1);
  }
}

__global__ void offs_kernel(const int* __restrict__ counts, int* __restrict__ offs,
                            int* __restrict__ cursors) {
  if (threadIdx.x == 0) {
    int r = 0;
    for (int e = 0; e < NE; ++e) { offs[e] = r; cursors[e] = r; r += counts[e]; }
  }
}

__global__ void gather_kernel(const unsigned short* __restrict__ xb,
                              const int* __restrict__ topi, const float* __restrict__ topv,
                              int* __restrict__ cursors, unsigned short* __restrict__ xg,
                              int* __restrict__ row_token, float* __restrict__ row_gate,
                              int* __restrict__ row_of) {
  const int wave = threadIdx.x >> 6, lane = threadIdx.x & 63;
  const int t = blockIdx.x * 4 + wave;
  const uint4* src = (const uint4*)(xb + (size_t)t * HD);
#pragma unroll
  for (int j = 0; j < 2; ++j) {
    const int e = topi[2 * t + j];
    int pos = 0;
    if (lane == 0) {
      pos = atomicAdd(&cursors[e], 1);
      row_token[pos] = t;
      row_gate[pos] = topv[2 * t + j];
      row_of[2 * t + j] = pos;
    }
    pos = __shfl(pos, 0);
    uint4* dst = (uint4*)(xg + (size_t)pos * HD);
#pragma unroll
    for (int c = lane; c < 256; c += 64) dst[c] = src[c];
  }
}

// ---------------- pipelined pack: f32 [K][N] -> bf16 B^T [N][K] ----------------
// 4 k-tiles per block; next tile's f32 loads issued before current tile's
// transpose+store (HBM latency hidden); double LDS buffer, 1 sync/tile.
template <int K, int N>
__global__ __launch_bounds__(256) void pack_wt4(const float* __restrict__ we,
                                                const float* __restrict__ ws,
                                                unsigned short* __restrict__ dstw) {
  const int e = blockIdx.z;
  const float* src = (e < NE) ? (we + (size_t)e * K * N) : (ws + (size_t)(e - NE) * K * N);
  unsigned short* dst = dstw + (size_t)e * K * N;
  const int nt = blockIdx.x * 64;
  const int kt0 = blockIdx.y * 256;
  __shared__ unsigned short ps[2][64 * 73];
  const int tid = threadIdx.x;
  const int lr = tid >> 2, lc = (tid & 3) * 16;   // loader: row, col (16 floats)
  const int nr = tid >> 2, kc = (tid & 3) * 16;   // transposer: n, k-base
  float4 ra[4], rb[4];
  {
    const float* sp = src + (size_t)(kt0 + lr) * N + nt + lc;
    ra[0] = *(const float4*)sp;       ra[1] = *(const float4*)(sp + 4);
    ra[2] = *(const float4*)(sp + 8); ra[3] = *(const float4*)(sp + 12);
  }
#pragma unroll
  for (int t = 0; t < 4; ++t) {
    if (t < 3) {
      const float* sp = src + (size_t)(kt0 + (t + 1) * 64 + lr) * N + nt + lc;
      rb[0] = *(const float4*)sp;       rb[1] = *(const float4*)(sp + 4);
      rb[2] = *(const float4*)(sp + 8); rb[3] = *(const float4*)(sp + 12);
    }
    unsigned short* pb = ps[t & 1];
    {
      unsigned short* tp = pb + lr * 73 + lc;
#pragma unroll
      for (int q = 0; q < 4; ++q) {
        const float4 v = ra[q];
        tp[4 * q + 0] = f2bf(v.x); tp[4 * q + 1] = f2bf(v.y);
        tp[4 * q + 2] = f2bf(v.z); tp[4 * q + 3] = f2bf(v.w);
      }
    }
    __syncthreads();
    {
      unsigned u[8];
#pragma unroll
      for (int j = 0; j < 8; ++j)
        u[j] = (unsigned)pb[(kc + 2 * j) * 73 + nr] |
               ((unsigned)pb[(kc + 2 * j + 1) * 73 + nr] << 16);
      unsigned short* dp = dst + (size_t)(nt + nr) * K + kt0 + t * 64 + kc;
      uint4 v0; v0.x = u[0]; v0.y = u[1]; v0.z = u[2]; v0.w = u[3];
      uint4 v1; v1.x = u[4]; v1.y = u[5]; v1.z = u[6]; v1.w = u[7];
      *(uint4*)dp = v0;
      *(uint4*)(dp + 8) = v1;
    }
    ra[0] = rb[0]; ra[1] = rb[1]; ra[2] = rb[2]; ra[3] = rb[3];
  }
}

// ---------------- frag read / mfma helpers ----------
template <int MS>
__device__ __forceinline__ void rd_a(bf16x8 (&d)[8], const unsigned short* base,
                                     int wr, int fr, int fq, int swz) {
#pragma unroll
  for (int mi = 0; mi < 4; ++mi)
#pragma unroll
    for (int ks = 0; ks < 2; ++ks)
      d[mi * 2 + ks] = *(const bf16x8*)(base + (wr * 128 + MS * 64 + mi * 16 + fr) * 64 +
                                        (((ks * 4 + fq) ^ swz) << 3));
}
template <int NSUB>
__device__ __forceinline__ void rd_b(bf16x8 (&d)[4], const unsigned short* base,
                                     int wc, int fr, int fq, int swz) {
#pragma unroll
  for (int ni = 0; ni < 2; ++ni)
#pragma unroll
    for (int ks = 0; ks < 2; ++ks)
      d[ni * 2 + ks] = *(const bf16x8*)(base + (wc * 64 + NSUB * 32 + ni * 16 + fr) * 64 +
                                        (((ks * 4 + fq) ^ swz) << 3));
}
template <int MS, int NSUB>
__device__ __forceinline__ void mm16(f32x4 (&acc)[8][4], const bf16x8 (&a)[8],
                                     const bf16x8 (&b)[4]) {
  __builtin_amdgcn_s_setprio(1);
#pragma unroll
  for (int mi = 0; mi < 4; ++mi)
#pragma unroll
    for (int ni = 0; ni < 2; ++ni)
#pragma unroll
      for (int ks = 0; ks < 2; ++ks)
        acc[MS * 4 + mi][NSUB * 2 + ni] = __builtin_amdgcn_mfma_f32_16x16x32_bf16(
            a[mi * 2 + ks], b[ni * 2 + ks], acc[MS * 4 + mi][NSUB * 2 + ni], 0, 0, 0);
  __builtin_amdgcn_s_setprio(0);
}

// =======================================================================
// Register-pipelined K-loop (R10 schedule) with dual-base K-concat support.
// =======================================================================
template <int K>
__device__ __forceinline__ void kloop(
    const unsigned short* __restrict__ A, const unsigned short* __restrict__ A2,
    const unsigned short* __restrict__ Bt, const unsigned short* __restrict__ Bt2,
    int ksw, unsigned short* smem, int m0, int n0, f32x4 (&acc)[8][4],
    int wr, int wc, int fr, int fq, int swz,
    int wrA, int wcB, int lr8, int lc8, int scol, int nkt) {
#define SAK(s, kt, b)                                                          \
  { int kl_ = (kt); const unsigned short* ab_ = A;                             \
    if (kl_ >= ksw) { ab_ = A2; kl_ -= ksw; }                                  \
    const int r0_ = wrA + (s) * 64 + lr8;                                      \
    const unsigned short* s_ = ab_ + (size_t)(m0 + r0_) * K + kl_ * 64 + scol; \
    unsigned short* d_ = smem + (b) * 32768 + r0_ * 64 + lc8 * 8;              \
    GLDS16(s_, d_); GLDS16(s_ + (size_t)8 * K, d_ + 8 * 64); }
#define SBK(s, kt, b)                                                          \
  { int kl_ = (kt); const unsigned short* bb_ = Bt;                            \
    if (kl_ >= ksw) { bb_ = Bt2; kl_ -= ksw; }                                 \
    const int r0_ = wcB + (s) * 32 + lr8;                                      \
    const unsigned short* s_ = bb_ + (size_t)(n0 + r0_) * K + kl_ * 64 + scol; \
    unsigned short* d_ = smem + (b) * 32768 + 16384 + r0_ * 64 + lc8 * 8;      \
    GLDS16(s_, d_); GLDS16(s_ + (size_t)8 * K, d_ + 8 * 64); }

  SAK(0, 0, 0); SAK(1, 0, 0); SBK(0, 0, 0); SBK(1, 0, 0);
  SAK(0, 1, 1); SAK(1, 1, 1); SBK(0, 1, 1); SBK(1, 1, 1);
  asm volatile("s_waitcnt vmcnt(8)" ::: "memory");
  __builtin_amdgcn_s_barrier();

  bf16x8 a0[8], a1[8], b0[4], b1[4];
  rd_a<0>(a0, smem, wr, fr, fq, swz);
  rd_b<0>(b0, smem + 16384, wc, fr, fq, swz);

  for (int t = 0; t < nkt; ++t) {
    const int cur = t & 1;
    const int tp2 = (t + 2 < nkt) ? t + 2 : t;
    const unsigned short* As_c = smem + cur * 32768;
    const unsigned short* Bs_c = As_c + 16384;
    const unsigned short* As_n = smem + (cur ^ 1) * 32768;
    const unsigned short* Bs_n = As_n + 16384;
    // ---- ph0 ----
    rd_b<1>(b1, Bs_c, wc, fr, fq, swz);
    mm16<0, 0>(acc, a0, b0);
    // ---- ph1 ----
    rd_a<1>(a1, As_c, wr, fr, fq, swz);
    mm16<0, 1>(acc, a0, b1);
    asm volatile("s_waitcnt lgkmcnt(0)" ::: "memory");
    __builtin_amdgcn_s_barrier();
    __builtin_amdgcn_sched_barrier(0);
    // ---- ph2 ----
    SAK(0, tp2, cur); SBK(0, tp2, cur);
    mm16<1, 0>(acc, a1, b0);
    asm volatile("s_waitcnt vmcnt(4)" ::: "memory");
    __builtin_amdgcn_s_barrier();
    __builtin_amdgcn_sched_barrier(0);
    rd_a<0>(a0, As_n, wr, fr, fq, swz);
    rd_b<0>(b0, Bs_n, wc, fr, fq, swz);
    // ---- ph3 ----
    SAK(1, tp2, cur); SBK(1, tp2, cur);
    mm16<1, 1>(acc, a1, b1);
  }
#undef SAK
#undef SBK
}

// =======================================================================
// GEMM1: h = relu(A[M x 2048] * W1t^T + b1) -> bf16 hbuf.
// Routed slices: m-fast XCD map (uniform validity for runtime M).
// Shared slices (M==4096 known): inverted map — each XCD owns 2 m-bands x
// all n, so A (xb) is fetched once chip-wide instead of 8x.
// Invalid blocks pack W2 f32->bf16^T into wt2 (unchanged from R13).
// =======================================================================
__global__ __launch_bounds__(512, 2) void g1k(
    const unsigned short* __restrict__ Ash, const unsigned short* __restrict__ Art,
    const unsigned short* __restrict__ wt1,
    const float* __restrict__ bE, const float* __restrict__ bS,
    unsigned short* __restrict__ hout,
    const int* __restrict__ counts, const int* __restrict__ offs,
    int do_pack, const float* __restrict__ we_w2, const float* __restrict__ ws_w2,
    unsigned short* __restrict__ wt2) {
  constexpr int K = HD;
  constexpr int NBX = FF / 256;         // 32
  constexpr int NWG = NBX * 16;         // 512
  extern __shared__ unsigned short smem[];

  const int e = blockIdx.z;
  int M;
  const unsigned short* A;
  const float* bias;
  int hbase;
  if (e < NE) {
    M = counts[e];
    A = Art + (size_t)offs[e] * K;
    bias = bE + (size_t)e * FF;
    hbase = offs[e];
  } else {
    M = TOKENS;
    A = Ash;
    bias = bS + (size_t)(e - NE) * FF;
    hbase = 2 * TOKENS + (e - NE) * TOKENS;
  }
  const unsigned short* Bt = wt1 + (size_t)e * HD * FF;

  int flat = blockIdx.x + NBX * blockIdx.y;
  flat = (flat & 7) * (NWG >> 3) + (flat >> 3);
  int m0, n0;
  if (e < NE) {                       // m-fast (runtime M)
    m0 = (flat & 15) * 256;
    n0 = (flat >> 4) * 256;
  } else {                            // inverted: XCD owns 2 m-bands x 32 n
    const int xcd = flat >> 6;
    const int ii = flat & 63;
    m0 = (2 * xcd + (ii >> 5)) * 256;
    n0 = (ii & 31) * 256;
  }
  const int tid = threadIdx.x;

  if (m0 >= M) {
    if (!do_pack) return;
    int total = 0, prefix = 0;
    for (int e2 = 0; e2 < NE; ++e2) {
      int mb = (counts[e2] + 255) >> 8; if (mb > 16) mb = 16;
      const int inv = 32 * (16 - mb);
      if (e2 < e) prefix += inv;
      total += inv;
    }
    int mb_e = (counts[e] + 255) >> 8; if (mb_e > 16) mb_e = 16;
    const int m_idx = flat & 15, n_idx = flat >> 4;
    const int rank = prefix + n_idx * (16 - mb_e) + (m_idx - mb_e);
    unsigned short* ps = smem;  // [2][64][73]
    const int NT = 10 * 128 * 32;
    const int kk = tid >> 3, cc = (tid & 7) * 8;
    float4 r0a, r0b;
    int i = rank;
    if (i < NT) {
      const int e2 = i >> 12, rem = i & 4095, ktt = rem >> 5, ntt = rem & 31;
      const float* src = (e2 < NE) ? (we_w2 + (size_t)e2 * FF * HD)
                                   : (ws_w2 + (size_t)(e2 - NE) * FF * HD);
      const float* sp = src + (size_t)(ktt * 64 + kk) * HD + ntt * 64 + cc;
      r0a = *(const float4*)sp; r0b = *(const float4*)(sp + 4);
    }
    int it = 0;
    while (i < NT) {
      const int inext = i + total;
      float4 r1a, r1b;
      if (inext < NT) {
        const int e2 = inext >> 12, rem = inext & 4095, ktt = rem >> 5, ntt = rem & 31;
        const float* src = (e2 < NE) ? (we_w2 + (size_t)e2 * FF * HD)
                                     : (ws_w2 + (size_t)(e2 - NE) * FF * HD);
        const float* sp = src + (size_t)(ktt * 64 + kk) * HD + ntt * 64 + cc;
        r1a = *(const float4*)sp; r1b = *(const float4*)(sp + 4);
      }
      unsigned short* pb = ps + (it & 1) * (64 * 73);
      {
        unsigned short* tp = pb + kk * 73 + cc;
        tp[0] = f2bf(r0a.x); tp[1] = f2bf(r0a.y); tp[2] = f2bf(r0a.z); tp[3] = f2bf(r0a.w);
        tp[4] = f2bf(r0b.x); tp[5] = f2bf(r0b.y); tp[6] = f2bf(r0b.z); tp[7] = f2bf(r0b.w);
      }
      __syncthreads();
      {
        const int e2 = i >> 12, rem = i & 4095, ktt = rem >> 5, ntt = rem & 31;
        unsigned short* dst = wt2 + (size_t)e2 * HD * FF;
        const int nn = tid >> 3, kc = (tid & 7) * 8;
        unsigned u[4];
#pragma unroll
        for (int j = 0; j < 4; ++j)
          u[j] = (unsigned)pb[(kc + 2 * j) * 73 + nn] |
                 ((unsigned)pb[(kc + 2 * j + 1) * 73 + nn] << 16);
        uint4 v; v.x = u[0]; v.y = u[1]; v.z = u[2]; v.w = u[3];
        *(uint4*)(dst + (size_t)(ntt * 64 + nn) * FF + ktt * 64 + kc) = v;
      }
      r0a = r1a; r0b = r1b;
      i = inext; ++it;
    }
    return;
  }

  const int wid = tid >> 6, ln = tid & 63;
  const int wr = wid >> 2, wc = wid & 3;
  const int fr = ln & 15, fq = ln >> 4;
  const int swz = fr & 7;
  const int lr8 = ln >> 3;
  const int lc8 = ln & 7;
  const int scol = (lc8 ^ lr8) << 3;
  const int wrA = wr * 128 + wc * 16;
  const int wcB = wc * 64 + wr * 16;

  f32x4 acc[8][4];
#pragma unroll
  for (int i = 0; i < 8; ++i)
#pragma unroll
    for (int j = 0; j < 4; ++j) acc[i][j] = (f32x4){0.f, 0.f, 0.f, 0.f};

  kloop<K>(A, A, Bt, Bt, 1 << 30, smem, m0, n0, acc, wr, wc, fr, fq, swz,
           wrA, wcB, lr8, lc8, scol, K / 64);

#pragma unroll
  for (int nn = 0; nn < 4; ++nn) {
#pragma unroll
    for (int mm = 0; mm < 8; ++mm) {
      const int col = n0 + wc * 64 + (nn >> 1) * 32 + (nn & 1) * 16 + fr;
      const float bb = bias[col];
#pragma unroll
      for (int j = 0; j < 4; ++j) {
        const int r = m0 + wr * 128 + (mm >> 2) * 64 + (mm & 3) * 16 + fq * 4 + j;
        if (r < M) {
          float v = acc[mm][nn][j] + bb;
          v = v > 0.f ? v : 0.f;
          hout[(size_t)(hbase + r) * FF + col] = f2bf(v);
        }
      }
    }
  }
}

// =======================================================================
// GEMM2 (z=9): routed experts (z<8, m-fast map) + merged shared slice
// (z=8, K-concat nkt=256; inverted XCD map -> A fetched once, B L3-served).
// ybuf[row] = h * W2t^T + b2 (f32, no gate, no atomics).
// =======================================================================
__global__ __launch_bounds__(512, 2) void g2k(
    const unsigned short* __restrict__ hbuf, const unsigned short* __restrict__ wt2,
    const float* __restrict__ bE, const float* __restrict__ bS,
    float* __restrict__ ybuf,
    const int* __restrict__ counts, const int* __restrict__ offs) {
  constexpr int K = FF;
  constexpr int NBX = HD / 256;         // 8
  constexpr int NWG = NBX * 16;         // 128
  extern __shared__ unsigned short smem[];

  const int e = blockIdx.z;
  const bool merged = (e == NE);
  int M, nkt, ksw, hbase;
  const unsigned short *A, *A2, *B, *B2;
  const float *bias, *bias2;
  if (!merged) {
    M = counts[e];
    A = hbuf + (size_t)offs[e] * K;  A2 = A;
    B = wt2 + (size_t)e * HD * FF;   B2 = B;
    bias = bE + (size_t)e * HD;      bias2 = nullptr;
    hbase = offs[e];
    nkt = 128; ksw = 1 << 30;
  } else {
    M = TOKENS;
    A  = hbuf + (size_t)(2 * TOKENS) * K;
    A2 = hbuf + (size_t)(3 * TOKENS) * K;
    B  = wt2 + (size_t)NE * HD * FF;
    B2 = wt2 + (size_t)(NE + 1) * HD * FF;
    bias = bS;  bias2 = bS + HD;
    hbase = 2 * TOKENS;
    nkt = 256; ksw = 128;
  }

  int flat = blockIdx.x + NBX * blockIdx.y;
  flat = (flat & 7) * (NWG >> 3) + (flat >> 3);
  int m0, n0;
  if (!merged) {                      // m-fast (runtime M)
    m0 = (flat & 15) * 256;
    n0 = (flat >> 4) * 256;
  } else {                            // inverted: XCD owns 2 m-bands x 8 n
    const int xcd = flat >> 4;
    const int ii = flat & 15;
    m0 = (2 * xcd + (ii >> 3)) * 256;
    n0 = (ii & 7) * 256;
  }
  if (m0 >= M) return;

  const int tid = threadIdx.x;
  const int wid = tid >> 6, ln = tid & 63;
  const int wr = wid >> 2, wc = wid & 3;
  const int fr = ln & 15, fq = ln >> 4;
  const int swz = fr & 7;
  const int lr8 = ln >> 3;
  const int lc8 = ln & 7;
  const int scol = (lc8 ^ lr8) << 3;
  const int wrA = wr * 128 + wc * 16;
  const int wcB = wc * 64 + wr * 16;

  f32x4 acc[8][4];
#pragma unroll
  for (int i = 0; i < 8; ++i)
#pragma unroll
    for (int j = 0; j < 4; ++j) acc[i][j] = (f32x4){0.f, 0.f, 0.f, 0.f};

  kloop<K>(A, A2, B, B2, ksw, smem, m0, n0, acc, wr, wc, fr, fq, swz,
           wrA, wcB, lr8, lc8, scol, nkt);

#pragma unroll
  for (int nn = 0; nn < 4; ++nn) {
#pragma unroll
    for (int mm = 0; mm < 8; ++mm) {
      const int colw = wc * 64 + (nn >> 1) * 32 + (nn & 1) * 16 + fr;
      float bb = bias[n0 + colw];
      if (merged) bb += bias2[n0 + colw];
#pragma unroll
      for (int j = 0; j < 4; ++j) {
        const int r = m0 + wr * 128 + (mm >> 2) * 64 + (mm & 3) * 16 + fq * 4 + j;
        if (r < M)
          ybuf[(size_t)(hbase + r) * HD + n0 + colw] = acc[mm][nn][j] + bb;
      }
    }
  }
}

// ---------------- final reduce: out = s_merged + g0*ye0 + g1*ye1 ----------------
__global__ __launch_bounds__(256) void reduce_kernel(
    const float* __restrict__ ybuf, const int* __restrict__ row_of,
    const float* __restrict__ topv, float* __restrict__ out) {
  const int t = blockIdx.x;
  const int d = threadIdx.x * 8;
  const float g0 = topv[2 * t], g1 = topv[2 * t + 1];
  const float* y0 = ybuf + (size_t)row_of[2 * t] * HD + d;
  const float* y1 = ybuf + (size_t)row_of[2 * t + 1] * HD + d;
  const float* s0 = ybuf + (size_t)(2 * TOKENS + t) * HD + d;
  float* o = out + (size_t)t * HD + d;
#pragma unroll
  for (int q = 0; q < 2; ++q) {
    const float4 a = *(const float4*)(s0 + q * 4);
    const float4 c = *(const float4*)(y0 + q * 4);
    const float4 e = *(const float4*)(y1 + q * 4);
    float4 r;
    r.x = a.x + g0 * c.x + g1 * e.x;
    r.y = a.y + g0 * c.y + g1 * e.y;
    r.z = a.z + g0 * c.z + g1 * e.z;
    r.w = a.w + g0 * c.w + g1 * e.w;
    *(float4*)(o + q * 4) = r;
  }
}

extern "C" void kernel_launch(void* const* d_in, const int* in_sizes, int n_in,
                              void* d_out, int out_size, void* d_ws, size_t ws_size,
                              hipStream_t stream) {
  const float* x     = (const float*)d_in[0];
  const float* ws_w1 = (const float*)d_in[1];
  const float* ws_b1 = (const float*)d_in[2];
  const float* ws_w2 = (const float*)d_in[3];
  const float* ws_b2 = (const float*)d_in[4];
  const float* we_w1 = (const float*)d_in[5];
  const float* we_b1 = (const float*)d_in[6];
  const float* we_w2 = (const float*)d_in[7];
  const float* we_b2 = (const float*)d_in[8];
  const float* wg    = (const float*)d_in[9];

  float* out = (float*)d_out;
  float* logits = out + (size_t)TOKENS * HD;

  hipFuncSetAttribute(reinterpret_cast<const void*>(g1k),
                      hipFuncAttributeMaxDynamicSharedMemorySize, 131072);
  hipFuncSetAttribute(reinterpret_cast<const void*>(g2k),
                      hipFuncAttributeMaxDynamicSharedMemorySize, 131072);

  char* ws = (char*)d_ws;
  unsigned short* wt1  = (unsigned short*)ws;                   // 335,544,320
  unsigned short* wt2  = (unsigned short*)(ws + 335544320);     // 335,544,320
  unsigned short* xb   = (unsigned short*)(ws + 671088640);     //  16,777,216
  unsigned short* xg   = (unsigned short*)(ws + 687865856);     //  34,078,720
  unsigned short* hbuf = (unsigned short*)(ws + 721944576);     // 268,435,456
  char* ctrl = ws + 990380032;
  float* ybuf = (float*)ws;   // alias wt1 (dead by GEMM2): 12288 rows = 100 MB
  int*   row_token = (int*)(ctrl);
  float* row_gate  = (float*)(ctrl + 32768);
  int*   topi      = (int*)(ctrl + 65536);
  float* topv      = (float*)(ctrl + 98304);
  int*   counts    = (int*)(ctrl + 131072);
  int*   offs      = (int*)(ctrl + 131104);
  int*   cursors   = (int*)(ctrl + 131136);
  int*   row_of    = (int*)(ctrl + 131168);

  hipMemsetAsync(counts, 0, NE * sizeof(int), stream);
  router_kernel<<<1024, 256, 0, stream>>>(x, wg, logits, topi, topv, counts, xb);
  offs_kernel<<<1, 64, 0, stream>>>(counts, offs, cursors);
  gather_kernel<<<1024, 256, 0, stream>>>(xb, topi, topv, cursors, xg,
                                          row_token, row_gate, row_of);
  pack_wt4<HD, FF><<<dim3(FF / 64, HD / 256, 10), 256, 0, stream>>>(we_w1, ws_w1, wt1);
  g1k<<<dim3(32, 16, 10), 512, 131072, stream>>>(
      xb, xg, wt1, we_b1, ws_b1, hbuf, counts, offs, 1, we_w2, ws_w2, wt2);
  g2k<<<dim3(8, 16, 9), 512, 131072, stream>>>(
      hbuf, wt2, we_b2, ws_b2, ybuf, counts, offs);
  reduce_kernel<<<TOKENS, 256, 0, stream>>>(ybuf, row_of, topv, out);

  (void)in_sizes; (void)n_in; (void)out_size; (void)ws_size;
}

// Round 16
// 1865.348 us; speedup vs baseline: 1.0069x; 1.0069x over previous
//
#include <hip/hip_runtime.h>

#define TOKENS 4096
#define HD 2048
#define FF 8192
#define NE 8
#define NS 2

typedef __attribute__((ext_vector_type(8))) short bf16x8;
typedef __attribute__((ext_vector_type(4))) float f32x4;

__device__ __forceinline__ unsigned rnd_bf(unsigned u) {
  return u + 0x7fffu + ((u >> 16) & 1u);
}
__device__ __forceinline__ unsigned short f2bf(float f) {
  unsigned u = __builtin_bit_cast(unsigned, f);
  return (unsigned short)(rnd_bf(u) >> 16);
}

#define GLDS16(gp, lp)                                                         \
  __builtin_amdgcn_global_load_lds(                                            \
      (const __attribute__((address_space(1))) unsigned*)(const void*)(gp),    \
      (__attribute__((address_space(3))) unsigned*)(lp), 16, 0, 0)

// ---------------- router (fused: also emits xb bf16) ----------------
__global__ void router_kernel(const float* __restrict__ x, const float* __restrict__ wg,
                              float* __restrict__ logits_out, int* __restrict__ topi,
                              float* __restrict__ topv, int* __restrict__ counts,
                              unsigned short* __restrict__ xb) {
  const int wave = threadIdx.x >> 6, lane = threadIdx.x & 63;
  const int t = blockIdx.x * 4 + wave;
  const float* xr = x + (size_t)t * HD;
  unsigned short* xbr = xb + (size_t)t * HD;
  float acc[8];
#pragma unroll
  for (int e = 0; e < 8; ++e) acc[e] = 0.f;
  for (int d = lane; d < HD; d += 64) {
    const float xv = xr[d];
    xbr[d] = f2bf(xv);
    const float4 w0 = *(const float4*)(wg + (size_t)d * 8);
    const float4 w1 = *(const float4*)(wg + (size_t)d * 8 + 4);
    acc[0] += xv * w0.x; acc[1] += xv * w0.y; acc[2] += xv * w0.z; acc[3] += xv * w0.w;
    acc[4] += xv * w1.x; acc[5] += xv * w1.y; acc[6] += xv * w1.z; acc[7] += xv * w1.w;
  }
#pragma unroll
  for (int e = 0; e < 8; ++e) {
#pragma unroll
    for (int off = 32; off > 0; off >>= 1) acc[e] += __shfl_xor(acc[e], off);
  }
  if (lane == 0) {
    *(float4*)(logits_out + (size_t)t * 8)     = make_float4(acc[0], acc[1], acc[2], acc[3]);
    *(float4*)(logits_out + (size_t)t * 8 + 4) = make_float4(acc[4], acc[5], acc[6], acc[7]);
    float mx = acc[0];
#pragma unroll
    for (int e = 1; e < 8; ++e) mx = fmaxf(mx, acc[e]);
    float p[8], s = 0.f;
#pragma unroll
    for (int e = 0; e < 8; ++e) { p[e] = expf(acc[e] - mx); s += p[e]; }
    const float inv = 1.f / s;
    int i1 = 0;
#pragma unroll
    for (int e = 1; e < 8; ++e) if (acc[e] > acc[i1]) i1 = e;
    int i2 = (i1 == 0) ? 1 : 0;
#pragma unroll
    for (int e = 0; e < 8; ++e) if (e != i1 && acc[e] > acc[i2]) i2 = e;
    topi[2 * t]     = i1; topv[2 * t]     = p[i1] * inv;
    topi[2 * t + 1] = i2; topv[2 * t + 1] = p[i2] * inv;
    atomicAdd(&counts[i1], 1);
    atomicAdd(&counts[i2], 1);
  }
}

__global__ void offs_kernel(const int* __restrict__ counts, int* __restrict__ offs,
                            int* __restrict__ cursors) {
  if (threadIdx.x == 0) {
    int r = 0;
    for (int e = 0; e < NE; ++e) { offs[e] = r; cursors[e] = r; r += counts[e]; }
  }
}

__global__ void gather_kernel(const unsigned short* __restrict__ xb,
                              const int* __restrict__ topi, const float* __restrict__ topv,
                              int* __restrict__ cursors, unsigned short* __restrict__ xg,
                              int* __restrict__ row_token, float* __restrict__ row_gate,
                              int* __restrict__ row_of) {
  const int wave = threadIdx.x >> 6, lane = threadIdx.x & 63;
  const int t = blockIdx.x * 4 + wave;
  const uint4* src = (const uint4*)(xb + (size_t)t * HD);
#pragma unroll
  for (int j = 0; j < 2; ++j) {
    const int e = topi[2 * t + j];
    int pos = 0;
    if (lane == 0) {
      pos = atomicAdd(&cursors[e], 1);
      row_token[pos] = t;
      row_gate[pos] = topv[2 * t + j];
      row_of[2 * t + j] = pos;
    }
    pos = __shfl(pos, 0);
    uint4* dst = (uint4*)(xg + (size_t)pos * HD);
#pragma unroll
    for (int c = lane; c < 256; c += 64) dst[c] = src[c];
  }
}

// ---------------- pipelined pack: f32 [K][N] -> bf16 B^T [N][K] ----------------
// 4 k-tiles/block; next tile's f32 reg-prefetch issued before current tile's
// transpose+store (HBM latency hidden); double LDS buffer, 1 sync/tile.
template <int K, int N>
__global__ __launch_bounds__(256) void pack_wt4(const float* __restrict__ we,
                                                const float* __restrict__ ws,
                                                unsigned short* __restrict__ dstw) {
  const int e = blockIdx.z;
  const float* src = (e < NE) ? (we + (size_t)e * K * N) : (ws + (size_t)(e - NE) * K * N);
  unsigned short* dst = dstw + (size_t)e * K * N;
  const int nt = blockIdx.x * 64;
  const int kt0 = blockIdx.y * 256;
  __shared__ unsigned short ps[2][64 * 73];
  const int tid = threadIdx.x;
  const int lr = tid >> 2, lc = (tid & 3) * 16;
  const int nr = tid >> 2, kc = (tid & 3) * 16;
  float4 ra[4], rb[4];
  {
    const float* sp = src + (size_t)(kt0 + lr) * N + nt + lc;
    ra[0] = *(const float4*)sp;       ra[1] = *(const float4*)(sp + 4);
    ra[2] = *(const float4*)(sp + 8); ra[3] = *(const float4*)(sp + 12);
  }
#pragma unroll
  for (int t = 0; t < 4; ++t) {
    if (t < 3) {
      const float* sp = src + (size_t)(kt0 + (t + 1) * 64 + lr) * N + nt + lc;
      rb[0] = *(const float4*)sp;       rb[1] = *(const float4*)(sp + 4);
      rb[2] = *(const float4*)(sp + 8); rb[3] = *(const float4*)(sp + 12);
    }
    unsigned short* pb = ps[t & 1];
    {
      unsigned short* tp = pb + lr * 73 + lc;
#pragma unroll
      for (int q = 0; q < 4; ++q) {
        const float4 v = ra[q];
        tp[4 * q + 0] = f2bf(v.x); tp[4 * q + 1] = f2bf(v.y);
        tp[4 * q + 2] = f2bf(v.z); tp[4 * q + 3] = f2bf(v.w);
      }
    }
    __syncthreads();
    {
      unsigned u[8];
#pragma unroll
      for (int j = 0; j < 8; ++j)
        u[j] = (unsigned)pb[(kc + 2 * j) * 73 + nr] |
               ((unsigned)pb[(kc + 2 * j + 1) * 73 + nr] << 16);
      unsigned short* dp = dst + (size_t)(nt + nr) * K + kt0 + t * 64 + kc;
      uint4 v0; v0.x = u[0]; v0.y = u[1]; v0.z = u[2]; v0.w = u[3];
      uint4 v1; v1.x = u[4]; v1.y = u[5]; v1.z = u[6]; v1.w = u[7];
      *(uint4*)dp = v0;
      *(uint4*)(dp + 8) = v1;
    }
    ra[0] = rb[0]; ra[1] = rb[1]; ra[2] = rb[2]; ra[3] = rb[3];
  }
}

// ---------------- frag read / mfma helpers ----------
template <int MS>
__device__ __forceinline__ void rd_a(bf16x8 (&d)[8], const unsigned short* base,
                                     int wr, int fr, int fq, int swz) {
#pragma unroll
  for (int mi = 0; mi < 4; ++mi)
#pragma unroll
    for (int ks = 0; ks < 2; ++ks)
      d[mi * 2 + ks] = *(const bf16x8*)(base + (wr * 128 + MS * 64 + mi * 16 + fr) * 64 +
                                        (((ks * 4 + fq) ^ swz) << 3));
}
template <int NSUB>
__device__ __forceinline__ void rd_b(bf16x8 (&d)[4], const unsigned short* base,
                                     int wc, int fr, int fq, int swz) {
#pragma unroll
  for (int ni = 0; ni < 2; ++ni)
#pragma unroll
    for (int ks = 0; ks < 2; ++ks)
      d[ni * 2 + ks] = *(const bf16x8*)(base + (wc * 64 + NSUB * 32 + ni * 16 + fr) * 64 +
                                        (((ks * 4 + fq) ^ swz) << 3));
}
template <int MS, int NSUB>
__device__ __forceinline__ void mm16(f32x4 (&acc)[8][4], const bf16x8 (&a)[8],
                                     const bf16x8 (&b)[4]) {
  __builtin_amdgcn_s_setprio(1);
#pragma unroll
  for (int mi = 0; mi < 4; ++mi)
#pragma unroll
    for (int ni = 0; ni < 2; ++ni)
#pragma unroll
      for (int ks = 0; ks < 2; ++ks)
        acc[MS * 4 + mi][NSUB * 2 + ni] = __builtin_amdgcn_mfma_f32_16x16x32_bf16(
            a[mi * 2 + ks], b[ni * 2 + ks], acc[MS * 4 + mi][NSUB * 2 + ni], 0, 0, 0);
  __builtin_amdgcn_s_setprio(0);
}

// =======================================================================
// Register-pipelined K-loop (R10 schedule) with dual-base K-concat support.
// =======================================================================
template <int K>
__device__ __forceinline__ void kloop(
    const unsigned short* __restrict__ A, const unsigned short* __restrict__ A2,
    const unsigned short* __restrict__ Bt, const unsigned short* __restrict__ Bt2,
    int ksw, unsigned short* smem, int m0, int n0, f32x4 (&acc)[8][4],
    int wr, int wc, int fr, int fq, int swz,
    int wrA, int wcB, int lr8, int lc8, int scol, int nkt) {
#define SAK(s, kt, b)                                                          \
  { int kl_ = (kt); const unsigned short* ab_ = A;                             \
    if (kl_ >= ksw) { ab_ = A2; kl_ -= ksw; }                                  \
    const int r0_ = wrA + (s) * 64 + lr8;                                      \
    const unsigned short* s_ = ab_ + (size_t)(m0 + r0_) * K + kl_ * 64 + scol; \
    unsigned short* d_ = smem + (b) * 32768 + r0_ * 64 + lc8 * 8;              \
    GLDS16(s_, d_); GLDS16(s_ + (size_t)8 * K, d_ + 8 * 64); }
#define SBK(s, kt, b)                                                          \
  { int kl_ = (kt); const unsigned short* bb_ = Bt;                            \
    if (kl_ >= ksw) { bb_ = Bt2; kl_ -= ksw; }                                 \
    const int r0_ = wcB + (s) * 32 + lr8;                                      \
    const unsigned short* s_ = bb_ + (size_t)(n0 + r0_) * K + kl_ * 64 + scol; \
    unsigned short* d_ = smem + (b) * 32768 + 16384 + r0_ * 64 + lc8 * 8;      \
    GLDS16(s_, d_); GLDS16(s_ + (size_t)8 * K, d_ + 8 * 64); }

  SAK(0, 0, 0); SAK(1, 0, 0); SBK(0, 0, 0); SBK(1, 0, 0);
  SAK(0, 1, 1); SAK(1, 1, 1); SBK(0, 1, 1); SBK(1, 1, 1);
  asm volatile("s_waitcnt vmcnt(8)" ::: "memory");
  __builtin_amdgcn_s_barrier();

  bf16x8 a0[8], a1[8], b0[4], b1[4];
  rd_a<0>(a0, smem, wr, fr, fq, swz);
  rd_b<0>(b0, smem + 16384, wc, fr, fq, swz);

  for (int t = 0; t < nkt; ++t) {
    const int cur = t & 1;
    const int tp2 = (t + 2 < nkt) ? t + 2 : t;
    const unsigned short* As_c = smem + cur * 32768;
    const unsigned short* Bs_c = As_c + 16384;
    const unsigned short* As_n = smem + (cur ^ 1) * 32768;
    const unsigned short* Bs_n = As_n + 16384;
    // ---- ph0 ----
    rd_b<1>(b1, Bs_c, wc, fr, fq, swz);
    mm16<0, 0>(acc, a0, b0);
    // ---- ph1 ----
    rd_a<1>(a1, As_c, wr, fr, fq, swz);
    mm16<0, 1>(acc, a0, b1);
    asm volatile("s_waitcnt lgkmcnt(0)" ::: "memory");
    __builtin_amdgcn_s_barrier();
    __builtin_amdgcn_sched_barrier(0);
    // ---- ph2 ----
    SAK(0, tp2, cur); SBK(0, tp2, cur);
    mm16<1, 0>(acc, a1, b0);
    asm volatile("s_waitcnt vmcnt(4)" ::: "memory");
    __builtin_amdgcn_s_barrier();
    __builtin_amdgcn_sched_barrier(0);
    rd_a<0>(a0, As_n, wr, fr, fq, swz);
    rd_b<0>(b0, Bs_n, wc, fr, fq, swz);
    // ---- ph3 ----
    SAK(1, tp2, cur); SBK(1, tp2, cur);
    mm16<1, 1>(acc, a1, b1);
  }
#undef SAK
#undef SBK
}

// =======================================================================
// GEMM1: h = relu(A[M x 2048] * W1t^T + b1) -> bf16 hbuf.
// Invalid blocks pack W2 f32->bf16^T into wt2 (reg-prefetched, stride-73,
// double LDS buffer) — R13 form (pack hiding measured nearly free).
// =======================================================================
__global__ __launch_bounds__(512, 2) void g1k(
    const unsigned short* __restrict__ Ash, const unsigned short* __restrict__ Art,
    const unsigned short* __restrict__ wt1,
    const float* __restrict__ bE, const float* __restrict__ bS,
    unsigned short* __restrict__ hout,
    const int* __restrict__ counts, const int* __restrict__ offs,
    int do_pack, const float* __restrict__ we_w2, const float* __restrict__ ws_w2,
    unsigned short* __restrict__ wt2) {
  constexpr int K = HD;
  constexpr int NBX = FF / 256;         // 32
  constexpr int NWG = NBX * 16;         // 512
  extern __shared__ unsigned short smem[];

  const int e = blockIdx.z;
  int M;
  const unsigned short* A;
  const float* bias;
  int hbase;
  if (e < NE) {
    M = counts[e];
    A = Art + (size_t)offs[e] * K;
    bias = bE + (size_t)e * FF;
    hbase = offs[e];
  } else {
    M = TOKENS;
    A = Ash;
    bias = bS + (size_t)(e - NE) * FF;
    hbase = 2 * TOKENS + (e - NE) * TOKENS;
  }
  const unsigned short* Bt = wt1 + (size_t)e * HD * FF;

  int flat = blockIdx.x + NBX * blockIdx.y;
  flat = (flat & 7) * (NWG >> 3) + (flat >> 3);
  const int m0 = (flat & 15) * 256;
  const int n0 = (flat >> 4) * 256;
  const int tid = threadIdx.x;

  if (m0 >= M) {
    if (!do_pack) return;
    int total = 0, prefix = 0;
    for (int e2 = 0; e2 < NE; ++e2) {
      int mb = (counts[e2] + 255) >> 8; if (mb > 16) mb = 16;
      const int inv = 32 * (16 - mb);
      if (e2 < e) prefix += inv;
      total += inv;
    }
    int mb_e = (counts[e] + 255) >> 8; if (mb_e > 16) mb_e = 16;
    const int m_idx = flat & 15, n_idx = flat >> 4;
    const int rank = prefix + n_idx * (16 - mb_e) + (m_idx - mb_e);
    unsigned short* ps = smem;  // [2][64][73]
    const int NT = 10 * 128 * 32;
    const int kk = tid >> 3, cc = (tid & 7) * 8;
    float4 r0a, r0b;
    int i = rank;
    if (i < NT) {
      const int e2 = i >> 12, rem = i & 4095, ktt = rem >> 5, ntt = rem & 31;
      const float* src = (e2 < NE) ? (we_w2 + (size_t)e2 * FF * HD)
                                   : (ws_w2 + (size_t)(e2 - NE) * FF * HD);
      const float* sp = src + (size_t)(ktt * 64 + kk) * HD + ntt * 64 + cc;
      r0a = *(const float4*)sp; r0b = *(const float4*)(sp + 4);
    }
    int it = 0;
    while (i < NT) {
      const int inext = i + total;
      float4 r1a, r1b;
      if (inext < NT) {
        const int e2 = inext >> 12, rem = inext & 4095, ktt = rem >> 5, ntt = rem & 31;
        const float* src = (e2 < NE) ? (we_w2 + (size_t)e2 * FF * HD)
                                     : (ws_w2 + (size_t)(e2 - NE) * FF * HD);
        const float* sp = src + (size_t)(ktt * 64 + kk) * HD + ntt * 64 + cc;
        r1a = *(const float4*)sp; r1b = *(const float4*)(sp + 4);
      }
      unsigned short* pb = ps + (it & 1) * (64 * 73);
      {
        unsigned short* tp = pb + kk * 73 + cc;
        tp[0] = f2bf(r0a.x); tp[1] = f2bf(r0a.y); tp[2] = f2bf(r0a.z); tp[3] = f2bf(r0a.w);
        tp[4] = f2bf(r0b.x); tp[5] = f2bf(r0b.y); tp[6] = f2bf(r0b.z); tp[7] = f2bf(r0b.w);
      }
      __syncthreads();
      {
        const int e2 = i >> 12, rem = i & 4095, ktt = rem >> 5, ntt = rem & 31;
        unsigned short* dst = wt2 + (size_t)e2 * HD * FF;
        const int nn = tid >> 3, kc = (tid & 7) * 8;
        unsigned u[4];
#pragma unroll
        for (int j = 0; j < 4; ++j)
          u[j] = (unsigned)pb[(kc + 2 * j) * 73 + nn] |
                 ((unsigned)pb[(kc + 2 * j + 1) * 73 + nn] << 16);
        uint4 v; v.x = u[0]; v.y = u[1]; v.z = u[2]; v.w = u[3];
        *(uint4*)(dst + (size_t)(ntt * 64 + nn) * FF + ktt * 64 + kc) = v;
      }
      r0a = r1a; r0b = r1b;
      i = inext; ++it;
    }
    return;
  }

  const int wid = tid >> 6, ln = tid & 63;
  const int wr = wid >> 2, wc = wid & 3;
  const int fr = ln & 15, fq = ln >> 4;
  const int swz = fr & 7;
  const int lr8 = ln >> 3;
  const int lc8 = ln & 7;
  const int scol = (lc8 ^ lr8) << 3;
  const int wrA = wr * 128 + wc * 16;
  const int wcB = wc * 64 + wr * 16;

  f32x4 acc[8][4];
#pragma unroll
  for (int i = 0; i < 8; ++i)
#pragma unroll
    for (int j = 0; j < 4; ++j) acc[i][j] = (f32x4){0.f, 0.f, 0.f, 0.f};

  kloop<K>(A, A, Bt, Bt, 1 << 30, smem, m0, n0, acc, wr, wc, fr, fq, swz,
           wrA, wcB, lr8, lc8, scol, K / 64);

#pragma unroll
  for (int nn = 0; nn < 4; ++nn) {
#pragma unroll
    for (int mm = 0; mm < 8; ++mm) {
      const int col = n0 + wc * 64 + (nn >> 1) * 32 + (nn & 1) * 16 + fr;
      const float bb = bias[col];
#pragma unroll
      for (int j = 0; j < 4; ++j) {
        const int r = m0 + wr * 128 + (mm >> 2) * 64 + (mm & 3) * 16 + fq * 4 + j;
        if (r < M) {
          float v = acc[mm][nn][j] + bb;
          v = v > 0.f ? v : 0.f;
          hout[(size_t)(hbase + r) * FF + col] = f2bf(v);
        }
      }
    }
  }
}

// =======================================================================
// GEMM2 (z=9): routed experts (z<8) + merged shared slice (z=8, K-concat,
// nkt=256, base switch at 128). ybuf[row] = h * W2t^T + b2.
// =======================================================================
__global__ __launch_bounds__(512, 2) void g2k(
    const unsigned short* __restrict__ hbuf, const unsigned short* __restrict__ wt2,
    const float* __restrict__ bE, const float* __restrict__ bS,
    float* __restrict__ ybuf,
    const int* __restrict__ counts, const int* __restrict__ offs) {
  constexpr int K = FF;
  constexpr int NBX = HD / 256;         // 8
  constexpr int NWG = NBX * 16;         // 128
  extern __shared__ unsigned short smem[];

  const int e = blockIdx.z;
  const bool merged = (e == NE);
  int M, nkt, ksw, hbase;
  const unsigned short *A, *A2, *B, *B2;
  const float *bias, *bias2;
  if (!merged) {
    M = counts[e];
    A = hbuf + (size_t)offs[e] * K;  A2 = A;
    B = wt2 + (size_t)e * HD * FF;   B2 = B;
    bias = bE + (size_t)e * HD;      bias2 = nullptr;
    hbase = offs[e];
    nkt = 128; ksw = 1 << 30;
  } else {
    M = TOKENS;
    A  = hbuf + (size_t)(2 * TOKENS) * K;
    A2 = hbuf + (size_t)(3 * TOKENS) * K;
    B  = wt2 + (size_t)NE * HD * FF;
    B2 = wt2 + (size_t)(NE + 1) * HD * FF;
    bias = bS;  bias2 = bS + HD;
    hbase = 2 * TOKENS;
    nkt = 256; ksw = 128;
  }

  int flat = blockIdx.x + NBX * blockIdx.y;
  flat = (flat & 7) * (NWG >> 3) + (flat >> 3);
  const int m0 = (flat & 15) * 256;
  const int n0 = (flat >> 4) * 256;
  if (m0 >= M) return;

  const int tid = threadIdx.x;
  const int wid = tid >> 6, ln = tid & 63;
  const int wr = wid >> 2, wc = wid & 3;
  const int fr = ln & 15, fq = ln >> 4;
  const int swz = fr & 7;
  const int lr8 = ln >> 3;
  const int lc8 = ln & 7;
  const int scol = (lc8 ^ lr8) << 3;
  const int wrA = wr * 128 + wc * 16;
  const int wcB = wc * 64 + wr * 16;

  f32x4 acc[8][4];
#pragma unroll
  for (int i = 0; i < 8; ++i)
#pragma unroll
    for (int j = 0; j < 4; ++j) acc[i][j] = (f32x4){0.f, 0.f, 0.f, 0.f};

  kloop<K>(A, A2, B, B2, ksw, smem, m0, n0, acc, wr, wc, fr, fq, swz,
           wrA, wcB, lr8, lc8, scol, nkt);

#pragma unroll
  for (int nn = 0; nn < 4; ++nn) {
#pragma unroll
    for (int mm = 0; mm < 8; ++mm) {
      const int colw = wc * 64 + (nn >> 1) * 32 + (nn & 1) * 16 + fr;
      float bb = bias[n0 + colw];
      if (merged) bb += bias2[n0 + colw];
#pragma unroll
      for (int j = 0; j < 4; ++j) {
        const int r = m0 + wr * 128 + (mm >> 2) * 64 + (mm & 3) * 16 + fq * 4 + j;
        if (r < M)
          ybuf[(size_t)(hbase + r) * HD + n0 + colw] = acc[mm][nn][j] + bb;
      }
    }
  }
}

// ---------------- final reduce: out = s_merged + g0*ye0 + g1*ye1 ----------------
__global__ __launch_bounds__(256) void reduce_kernel(
    const float* __restrict__ ybuf, const int* __restrict__ row_of,
    const float* __restrict__ topv, float* __restrict__ out) {
  const int t = blockIdx.x;
  const int d = threadIdx.x * 8;
  const float g0 = topv[2 * t], g1 = topv[2 * t + 1];
  const float* y0 = ybuf + (size_t)row_of[2 * t] * HD + d;
  const float* y1 = ybuf + (size_t)row_of[2 * t + 1] * HD + d;
  const float* s0 = ybuf + (size_t)(2 * TOKENS + t) * HD + d;
  float* o = out + (size_t)t * HD + d;
#pragma unroll
  for (int q = 0; q < 2; ++q) {
    const float4 a = *(const float4*)(s0 + q * 4);
    const float4 c = *(const float4*)(y0 + q * 4);
    const float4 e = *(const float4*)(y1 + q * 4);
    float4 r;
    r.x = a.x + g0 * c.x + g1 * e.x;
    r.y = a.y + g0 * c.y + g1 * e.y;
    r.z = a.z + g0 * c.z + g1 * e.z;
    r.w = a.w + g0 * c.w + g1 * e.w;
    *(float4*)(o + q * 4) = r;
  }
}

extern "C" void kernel_launch(void* const* d_in, const int* in_sizes, int n_in,
                              void* d_out, int out_size, void* d_ws, size_t ws_size,
                              hipStream_t stream) {
  const float* x     = (const float*)d_in[0];
  const float* ws_w1 = (const float*)d_in[1];
  const float* ws_b1 = (const float*)d_in[2];
  const float* ws_w2 = (const float*)d_in[3];
  const float* ws_b2 = (const float*)d_in[4];
  const float* we_w1 = (const float*)d_in[5];
  const float* we_b1 = (const float*)d_in[6];
  const float* we_w2 = (const float*)d_in[7];
  const float* we_b2 = (const float*)d_in[8];
  const float* wg    = (const float*)d_in[9];

  float* out = (float*)d_out;
  float* logits = out + (size_t)TOKENS * HD;

  hipFuncSetAttribute(reinterpret_cast<const void*>(g1k),
                      hipFuncAttributeMaxDynamicSharedMemorySize, 131072);
  hipFuncSetAttribute(reinterpret_cast<const void*>(g2k),
                      hipFuncAttributeMaxDynamicSharedMemorySize, 131072);

  char* ws = (char*)d_ws;
  unsigned short* wt1  = (unsigned short*)ws;                   // 335,544,320
  unsigned short* wt2  = (unsigned short*)(ws + 335544320);     // 335,544,320
  unsigned short* xb   = (unsigned short*)(ws + 671088640);     //  16,777,216
  unsigned short* xg   = (unsigned short*)(ws + 687865856);     //  34,078,720
  unsigned short* hbuf = (unsigned short*)(ws + 721944576);     // 268,435,456
  char* ctrl = ws + 990380032;
  float* ybuf = (float*)ws;   // alias wt1 (dead by GEMM2): 12288 rows = 100 MB
  int*   row_token = (int*)(ctrl);
  float* row_gate  = (float*)(ctrl + 32768);
  int*   topi      = (int*)(ctrl + 65536);
  float* topv      = (float*)(ctrl + 98304);
  int*   counts    = (int*)(ctrl + 131072);
  int*   offs      = (int*)(ctrl + 131104);
  int*   cursors   = (int*)(ctrl + 131136);
  int*   row_of    = (int*)(ctrl + 131168);

  hipMemsetAsync(counts, 0, NE * sizeof(int), stream);
  router_kernel<<<1024, 256, 0, stream>>>(x, wg, logits, topi, topv, counts, xb);
  offs_kernel<<<1, 64, 0, stream>>>(counts, offs, cursors);
  gather_kernel<<<1024, 256, 0, stream>>>(xb, topi, topv, cursors, xg,
                                          row_token, row_gate, row_of);
  // pack W1 (pipelined 4-tile blocks) -> wt1
  pack_wt4<HD, FF><<<dim3(FF / 64, HD / 256, 10), 256, 0, stream>>>(we_w1, ws_w1, wt1);
  // GEMM1 (invalid blocks pack W2 -> wt2, hidden)
  g1k<<<dim3(32, 16, 10), 512, 131072, stream>>>(
      xb, xg, wt1, we_b1, ws_b1, hbuf, counts, offs, 1, we_w2, ws_w2, wt2);
  // GEMM2 -> ybuf
  g2k<<<dim3(8, 16, 9), 512, 131072, stream>>>(
      hbuf, wt2, we_b2, ws_b2, ybuf, counts, offs);
  reduce_kernel<<<TOKENS, 256, 0, stream>>>(ybuf, row_of, topv, out);

  (void)in_sizes; (void)n_in; (void)out_size; (void)ws_size;
}